// Round 10
// baseline (4028.534 us; speedup 1.0000x reference)
//
#include <hip/hip_runtime.h>
#include <math.h>

// SPINN forward, fp32 throughout (argmax trajectory sensitivity forbids bf16/f16).
// 2 launches/step, uniform 512-block grids (round-6 champion structure):
//   A (k_gemm, 512 blk x 256 thr): fused GEMM [gates-x 12x16 || lstm5 8x40], acc 8x4,
//     KS=128. W is read DIRECTLY from global per-kk (16-lane broadcast of a contiguous
//     256B row segment, L1-resident 32KB tile) -> LDS holds only A. LDS-pipe cycles
//     drop ~41K -> ~27.5K /CU (~17 -> ~11.5 us bound). KT=64 (As 33.8KB, 2 blk/CU).
//   B (k_B, 512 blk = row x 4 j-slices): gather + LSTM + argmax + hh-GEMM + track-GEMM
//     + node + stack + next-X. WhhT4/W3T4 are k-QUAD-interleaved ([k/4][n][4]) so the
//     GEMV loops use coalesced float4 loads: same bytes, bitwise-identical summation
//     order, 4x fewer load instructions.

#define B_ 128
#define CAP 40
#define XW 1536   // X row: [buf_h 0:512 | s1_h 512:1024 | s2_h 1024:1536]
#define GSPLIT 12
#define LSPLIT 8
#define NSTEP 64

__device__ __forceinline__ float sigm(float x) { return 1.f / (1.f + expf(-x)); }

// ---------------- repack weights ----------------
// W1T[k][n], k in [0,1536): W_ih[n][k].                               N=1024
// W2T[k][n], k in [0,1024): k<512 -> W_right[n][k], else W_left[n][k-512]. N=2560
// W3T4[k4][col][i] = W_track[col][4*k4+i]   (64 x 2560 x 4)
// WhhT4[k4][n][i]  = W_hh[n][4*k4+i]        (64 x 1024 x 4)
__global__ void k_repack(const float* __restrict__ W_ih, const float* __restrict__ W_hh,
                         const float* __restrict__ W_left, const float* __restrict__ W_right,
                         const float* __restrict__ W_track, const float* __restrict__ b_ih,
                         const float* __restrict__ b_hh,
                         float* __restrict__ W1T, float* __restrict__ W2T,
                         float* __restrict__ W3T4, float* __restrict__ WhhT4,
                         float* __restrict__ b1) {
    size_t idx = (size_t)blockIdx.x * 256 + threadIdx.x;
    const size_t n1 = 1536ull * 1024ull;        // 1,572,864
    const size_t n2 = 1024ull * 2560ull;        // 2,621,440
    const size_t n3 = 64ull * 2560ull * 4ull;   //   655,360
    const size_t n4 = 64ull * 1024ull * 4ull;   //   262,144
    if (idx < n1) {
        int k = (int)(idx >> 10), n = (int)(idx & 1023);
        W1T[idx] = W_ih[(size_t)n * 1536 + k];
    } else if (idx < n1 + n2) {
        size_t r = idx - n1;
        int k = (int)(r / 2560), n = (int)(r % 2560);
        W2T[r] = (k < 512) ? W_right[(size_t)n * 512 + k] : W_left[(size_t)n * 512 + (k - 512)];
    } else if (idx < n1 + n2 + n3) {
        size_t r = idx - n1 - n2;
        int k4 = (int)(r / 10240);
        int rem = (int)(r % 10240);
        int col = rem >> 2, i = rem & 3;
        W3T4[r] = W_track[(size_t)col * 256 + k4 * 4 + i];
    } else if (idx < n1 + n2 + n3 + n4) {
        size_t r = idx - n1 - n2 - n3;
        int k4 = (int)(r >> 12);
        int rem = (int)(r & 4095);
        int n = rem >> 2, i = rem & 3;
        WhhT4[r] = W_hh[(size_t)n * 256 + k4 * 4 + i];
    } else if (idx < n1 + n2 + n3 + n4 + 1024) {
        int i = (int)(idx - n1 - n2 - n3 - n4);
        b1[i] = b_ih[i] + b_hh[i];
    }
}

// ---------------- init state ----------------
__global__ void k_init(const float* __restrict__ buffers, float* __restrict__ stack,
                       float* __restrict__ X, float* __restrict__ tc,
                       float* __restrict__ hh,
                       int* __restrict__ sptr, int* __restrict__ blen) {
    int b = blockIdx.x, t = threadIdx.x;
    const float* b0 = buffers + (size_t)b * 40 * 1024;      // buffers[b][0]
    const float* btop = b0 + 39 * 1024;                     // buffers[b][39]
    float* stk = stack + (size_t)b * CAP * 1024;
    for (int j = t; j < 1024; j += 256) { stk[j] = b0[j]; stk[1024 + j] = b0[j]; }
    float* Xb = X + (size_t)b * XW;
    for (int j = t; j < 512; j += 256) {
        Xb[j] = btop[j]; Xb[512 + j] = b0[j]; Xb[1024 + j] = b0[j];
    }
    tc[b * 256 + t] = 0.f;
    for (int j = t; j < 1024; j += 256) hh[(size_t)b * 1024 + j] = 0.f;  // th0 = 0
    if (t == 0) { sptr[b] = 2; blen[b] = 40; }
}

// ---------------- A: fused tiled fp32 GEMM (gates-x || lstm5-sub), k-split partials --
// [0,192):  gates-x: ks=bid>>4 (12), n0=(bid&15)*64, K-chunk=[ks*128,+128), aoff=0
// [192,512): lstm5:  ks=tI/40  (8),  n0=(tI%40)*64,  K-chunk=[ks*128,+128), aoff=512
// 256 threads: tile 128x64, thread-grid 16(m)x16(n), acc 8x4. A staged in LDS (KT=64);
// W read directly from global (16-lane broadcast, L1-resident 32KB tile).
__global__ __launch_bounds__(256, 2) void k_gemm(const float* __restrict__ X,
                                                 const float* __restrict__ W1T,
                                                 const float* __restrict__ W2T,
                                                 float* __restrict__ gpart,
                                                 float* __restrict__ lpart) {
    __shared__ float As[64][132];   // 33.8 KB
    const int bid = blockIdx.x;
    const float* WT; float* out; int N, n0, k0, aoff;
    if (bid < 192) {
        int ks = bid >> 4, nb = bid & 15;
        WT = W1T; out = gpart + (size_t)ks * 131072;
        N = 1024; n0 = nb * 64; k0 = ks * 128; aoff = 0;
    } else {
        int tI = bid - 192; int ks = tI / 40, nb = tI % 40;
        WT = W2T; out = lpart + (size_t)ks * 327680;
        N = 2560; n0 = nb * 64; k0 = ks * 128; aoff = 512;
    }
    const int tid = threadIdx.x;
    const int tm = tid >> 4;      // 0..15
    const int tn = tid & 15;      // 0..15

    float acc[8][4];
#pragma unroll
    for (int i = 0; i < 8; i++)
#pragma unroll
        for (int j = 0; j < 4; j++) acc[i][j] = 0.f;

    for (int ki = 0; ki < 128; ki += 64) {
        const int kb = k0 + ki;
        __syncthreads();
        {   // stage A: As[kk][m] = X[m][aoff+kb+kk]; 2 threads/row, 32 floats each
            int m = tid >> 1;
            int c0 = (tid & 1) * 32;
            const float4* src = (const float4*)(X + (size_t)m * XW + aoff + kb + c0);
#pragma unroll
            for (int j = 0; j < 8; j++) {
                float4 v = src[j];
                int kk = c0 + j * 4;
                As[kk + 0][m] = v.x; As[kk + 1][m] = v.y; As[kk + 2][m] = v.z; As[kk + 3][m] = v.w;
            }
        }
        __syncthreads();
        const float* wp = WT + (size_t)kb * N + n0 + tn * 4;
#pragma unroll 8
        for (int kk = 0; kk < 64; kk++) {
            float a[8], w[4];
            *(float4*)&a[0] = *(const float4*)&As[kk][tm * 4];
            *(float4*)&a[4] = *(const float4*)&As[kk][64 + tm * 4];
            *(float4*)&w[0] = *(const float4*)(wp + (size_t)kk * N);
#pragma unroll
            for (int i = 0; i < 8; i++)
#pragma unroll
                for (int j = 0; j < 4; j++) acc[i][j] += a[i] * w[j];
        }
    }
    float* base = out + n0 + tn * 4;
#pragma unroll
    for (int i = 0; i < 8; i++) {
        int m = (i < 4) ? (tm * 4 + i) : (64 + tm * 4 + (i - 4));
        *(float4*)(base + (size_t)m * N) = make_float4(acc[i][0], acc[i][1], acc[i][2], acc[i][3]);
    }
}

// ---------------- B: LSTM + argmax + hh-GEMM + track-GEMM + node + stack + next-X ----
// grid 512 = 128 rows x 4 j-slices (q). All 4 q-blocks of a row redundantly compute the
// LSTM/logits/argmax (deterministic, identical); slice work is split by q.
__global__ __launch_bounds__(256) void k_B(const float* __restrict__ gpart,
                                           const float* __restrict__ lpart,
                                           const float* __restrict__ hh_in,
                                           float* __restrict__ hh_out,
                                           const float* __restrict__ b1,
                                           const float* __restrict__ b_left,
                                           const float* __restrict__ W3T4,
                                           const float* __restrict__ WhhT4,
                                           const float* __restrict__ W_trans,
                                           const float* __restrict__ b_trans,
                                           const float* __restrict__ buffers,
                                           float* __restrict__ stack,
                                           float* __restrict__ X,
                                           const float* __restrict__ tc_in,
                                           float* __restrict__ tc_out,
                                           const int* __restrict__ sp_in,
                                           int* __restrict__ sp_out,
                                           const int* __restrict__ bl_in,
                                           int* __restrict__ bl_out,
                                           float* __restrict__ out_s) {
    const int bid = blockIdx.x;
    const int b = bid >> 2, q = bid & 3;
    const int t = threadIdx.x;
    const int sp = sp_in[b], bl = bl_in[b];
    __shared__ float sh_th[256];
    __shared__ float redw[4][4];
    __shared__ float shg[5][128];

    // 1) gather gates partials (12 splits + hh lump) + LSTM cell
    const float* gp = gpart + (size_t)b * 1024;
    const float* hp = hh_in + (size_t)b * 1024;
    float gi = b1[t] + hp[t],             gf = b1[256 + t] + hp[256 + t];
    float gg = b1[512 + t] + hp[512 + t], go = b1[768 + t] + hp[768 + t];
#pragma unroll 4
    for (int kc = 0; kc < GSPLIT; kc++) {
        const float* p = gp + (size_t)kc * 131072;
        gi += p[t]; gf += p[256 + t]; gg += p[512 + t]; go += p[768 + t];
    }
    float tcv = tc_in[b * 256 + t];
    float tcn = sigm(gf) * tcv + sigm(gi) * tanhf(gg);
    float thn = sigm(go) * tanhf(tcn);
    if ((t >> 6) == q) tc_out[b * 256 + t] = tcn;
    sh_th[t] = thn;

    // 2) logits via wave shfl reduction + argmax (all threads identically)
    float v0 = thn * W_trans[t],       v1 = thn * W_trans[256 + t];
    float v2 = thn * W_trans[512 + t], v3 = thn * W_trans[768 + t];
#pragma unroll
    for (int off = 32; off > 0; off >>= 1) {
        v0 += __shfl_down(v0, off); v1 += __shfl_down(v1, off);
        v2 += __shfl_down(v2, off); v3 += __shfl_down(v3, off);
    }
    if ((t & 63) == 0) {
        int w = t >> 6;
        redw[w][0] = v0; redw[w][1] = v1; redw[w][2] = v2; redw[w][3] = v3;
    }
    __syncthreads();                       // redw + sh_th ready
    float lg0 = redw[0][0] + redw[1][0] + redw[2][0] + redw[3][0] + b_trans[0];
    float lg1 = redw[0][1] + redw[1][1] + redw[2][1] + redw[3][1] + b_trans[1];
    float lg2 = redw[0][2] + redw[1][2] + redw[2][2] + redw[3][2] + b_trans[2];
    float lg3 = redw[0][3] + redw[1][3] + redw[2][3] + redw[3][3] + b_trans[3];
    int tr = 0; float best = lg0;
    if (lg1 > best) { best = lg1; tr = 1; }
    if (lg2 > best) { best = lg2; tr = 2; }
    if (lg3 > best) { best = lg3; tr = 3; }
    const bool do_shift = (tr == 3) && (bl > 2);
    const bool do_red   = (tr == 2) && (sp > 3);
    const int spn = sp + (do_shift ? 1 : 0) - (do_red ? 1 : 0);
    const int bln = bl - (do_shift ? 1 : 0);
    if (q == 0 && t == 0) {
        out_s[b * 4 + 0] = lg0; out_s[b * 4 + 1] = lg1;
        out_s[b * 4 + 2] = lg2; out_s[b * 4 + 3] = lg3;
        sp_out[b] = spn; bl_out[b] = bln;
    }
    float* stk = stack + (size_t)b * CAP * 1024;

    // 3) hh-GEMM for NEXT step's gates: k-quad-interleaved WhhT4, float4 coalesced.
    //    Summation grouping (k mod 4 -> h0..h3) identical to champion.
    {
        const float* wh = WhhT4 + (size_t)(q * 256 + t) * 4;
        float h0 = 0, h1 = 0, h2 = 0, h3 = 0;
#pragma unroll 8
        for (int k4 = 0; k4 < 64; k4++) {
            float4 w = *(const float4*)(wh + (size_t)k4 * 4096);
            h0 += sh_th[4 * k4]     * w.x;
            h1 += sh_th[4 * k4 + 1] * w.y;
            h2 += sh_th[4 * k4 + 2] * w.z;
            h3 += sh_th[4 * k4 + 3] * w.w;
        }
        hh_out[(size_t)b * 1024 + q * 256 + t] = (h0 + h1) + (h2 + h3);
    }

    // 4) reduce rows: lstm5 = sub-partials + b_left + W_track@th_new ; node.
    //    kh = t>>7: half-waves split the K range (128 each) and LSPLIT halves.
    //    W3T4 k-quad-interleaved: float4 loads, sequential-k order per accumulator.
    const int jj = t & 127, kh = t >> 7, j = q * 128 + jj;
    float node_h = 0.f;
    float a, ii, f1, f2, oo;
    if (do_red) {
        if (kh == 0) {
            a  = b_left[j];        ii = b_left[512 + j]; f1 = b_left[1024 + j];
            f2 = b_left[1536 + j]; oo = b_left[2048 + j];
        } else { a = ii = f1 = f2 = oo = 0.f; }
        const float* lp = lpart + (size_t)b * 2560;
        const int half = LSPLIT >> 1;
        for (int kc = kh * half; kc < kh * half + half; kc++) {
            const float* p = lp + (size_t)kc * 327680;
            a += p[j]; ii += p[512 + j]; f1 += p[1024 + j]; f2 += p[1536 + j]; oo += p[2048 + j];
        }
        const float* w = W3T4 + (size_t)j * 4;
#pragma unroll 4
        for (int k4 = kh * 32; k4 < kh * 32 + 32; k4++) {
            float t0 = sh_th[4 * k4],     t1 = sh_th[4 * k4 + 1];
            float t2 = sh_th[4 * k4 + 2], t3 = sh_th[4 * k4 + 3];
            const float* wk = w + (size_t)k4 * 10240;
            float4 wv;
            wv = *(const float4*)(wk);        a  += t0 * wv.x; a  += t1 * wv.y; a  += t2 * wv.z; a  += t3 * wv.w;
            wv = *(const float4*)(wk + 2048); ii += t0 * wv.x; ii += t1 * wv.y; ii += t2 * wv.z; ii += t3 * wv.w;
            wv = *(const float4*)(wk + 4096); f1 += t0 * wv.x; f1 += t1 * wv.y; f1 += t2 * wv.z; f1 += t3 * wv.w;
            wv = *(const float4*)(wk + 6144); f2 += t0 * wv.x; f2 += t1 * wv.y; f2 += t2 * wv.z; f2 += t3 * wv.w;
            wv = *(const float4*)(wk + 8192); oo += t0 * wv.x; oo += t1 * wv.y; oo += t2 * wv.z; oo += t3 * wv.w;
        }
        if (kh == 1) {
            shg[0][jj] = a; shg[1][jj] = ii; shg[2][jj] = f1; shg[3][jj] = f2; shg[4][jj] = oo;
        }
    }
    __syncthreads();                       // do_red is block-uniform
    if (do_red && kh == 0) {
        a += shg[0][jj]; ii += shg[1][jj]; f1 += shg[2][jj];
        f2 += shg[3][jj]; oo += shg[4][jj];
        float s1c = stk[(size_t)(sp - 1) * 1024 + 512 + j];
        float s2c = stk[(size_t)(sp - 2) * 1024 + 512 + j];
        float c = tanhf(a) * sigm(ii) + sigm(f1) * s2c + sigm(f2) * s1c;
        float h = sigm(oo) * tanhf(c);
        stk[(size_t)(sp - 2) * 1024 + j] = h;          // own-slice addresses only
        stk[(size_t)(sp - 2) * 1024 + 512 + j] = c;
        node_h = h;
    }
    // 5) shift: push buf_top (slot sp untouched by any read this step)
    if (do_shift) {
        const float* bt = buffers + ((size_t)b * 40 + (bl - 1)) * 1024;
        const int idx = q * 256 + t;
        stk[(size_t)sp * 1024 + idx] = bt[idx];
    }
    // 6) build next X (slice j, kh==0 threads)
    float* Xb = X + (size_t)b * XW;
    if (kh == 0) {
        const float* btn = buffers + ((size_t)b * 40 + (bln - 1)) * 1024;
        Xb[j] = btn[j];                                 // buf_top' h
        float s1h;
        if (do_red)        s1h = node_h;                // just-built node (register)
        else if (do_shift) s1h = buffers[((size_t)b * 40 + (bl - 1)) * 1024 + j];
        else               s1h = stk[(size_t)(sp - 1) * 1024 + j];
        Xb[512 + j] = s1h;
        Xb[1024 + j] = stk[(size_t)(spn - 2) * 1024 + j];  // untouched slot in all 3 cases
    }
}

// ---------------- host ----------------
extern "C" void kernel_launch(void* const* d_in, const int* in_sizes, int n_in,
                              void* d_out, int out_size, void* d_ws, size_t ws_size,
                              hipStream_t stream) {
    const float* buffers = (const float*)d_in[0];
    const float* W_left  = (const float*)d_in[1];
    const float* b_left  = (const float*)d_in[2];
    const float* W_right = (const float*)d_in[3];
    const float* W_track = (const float*)d_in[4];
    const float* W_ih    = (const float*)d_in[5];
    const float* W_hh    = (const float*)d_in[6];
    const float* b_ih    = (const float*)d_in[7];
    const float* b_hh    = (const float*)d_in[8];
    const float* W_trans = (const float*)d_in[9];
    const float* b_trans = (const float*)d_in[10];
    float* out = (float*)d_out;

    float* ws = (float*)d_ws;
    size_t off = 0;
    float* W1T   = ws + off; off += 1536ull * 1024;             // 1,572,864
    float* W2T   = ws + off; off += 1024ull * 2560;             // 2,621,440
    float* W3T4  = ws + off; off += 64ull * 2560 * 4;           //   655,360
    float* WhhT4 = ws + off; off += 64ull * 1024 * 4;           //   262,144
    float* b1    = ws + off; off += 1024;
    float* X     = ws + off; off += (size_t)B_ * XW;            //   196,608
    float* tc_a  = ws + off; off += (size_t)B_ * 256;
    float* tc_b  = ws + off; off += (size_t)B_ * 256;
    float* hh_a  = ws + off; off += (size_t)B_ * 1024;          //   131,072
    float* hh_b  = ws + off; off += (size_t)B_ * 1024;
    float* gpart = ws + off; off += (size_t)GSPLIT * 131072;    // 1,572,864
    float* lpart = ws + off; off += (size_t)LSPLIT * 327680;    // 2,621,440
    float* stack = ws + off; off += (size_t)B_ * CAP * 1024;    // 5,242,880
    int* sp_a = (int*)(ws + off); off += 128;
    int* sp_b = (int*)(ws + off); off += 128;
    int* bl_a = (int*)(ws + off); off += 128;
    int* bl_b = (int*)(ws + off); off += 128;

    {
        size_t total = 1536ull * 1024 + 1024ull * 2560 + 64ull * 2560 * 4
                     + 64ull * 1024 * 4 + 1024;
        int blocks = (int)((total + 255) / 256);
        k_repack<<<blocks, 256, 0, stream>>>(W_ih, W_hh, W_left, W_right, W_track, b_ih, b_hh,
                                             W1T, W2T, W3T4, WhhT4, b1);
        k_init<<<B_, 256, 0, stream>>>(buffers, stack, X, tc_a, hh_a, sp_a, bl_a);
    }

    for (int s = 0; s < NSTEP; s++) {
        k_gemm<<<512, 256, 0, stream>>>(X, W1T, W2T, gpart, lpart);
        const float* tci = (s & 1) ? tc_b : tc_a;  float* tco = (s & 1) ? tc_a : tc_b;
        const float* hhi = (s & 1) ? hh_b : hh_a;  float* hho = (s & 1) ? hh_a : hh_b;
        const int*   spi = (s & 1) ? sp_b : sp_a;  int*   spo = (s & 1) ? sp_a : sp_b;
        const int*   bli = (s & 1) ? bl_b : bl_a;  int*   blo = (s & 1) ? bl_a : bl_b;
        k_B<<<512, 256, 0, stream>>>(gpart, lpart, hhi, hho, b1, b_left, W3T4, WhhT4,
                                     W_trans, b_trans, buffers, stack, X, tci, tco,
                                     spi, spo, bli, blo, out + (size_t)s * B_ * 4);
    }
    (void)in_sizes; (void)n_in; (void)out_size; (void)ws_size;
}

// Round 11
// 2264.734 us; speedup vs baseline: 1.7788x; 1.7788x over previous
//
#include <hip/hip_runtime.h>
#include <math.h>

// SPINN forward, fp32 throughout (argmax trajectory sensitivity forbids bf16/f16).
// 2 launches/step, uniform 512-block grids. Recombination of proven halves:
//   A (k_gemm): round-6 champion — Ws staged in LDS, KT=32, acc 8x4, KS=128 (12/8
//     splits). Round-10 showed W-from-global per-kk costs 3.2x (load latency on the
//     FMA critical path at 2 blk/CU); LDS staging batches that latency.
//   B (k_B): round-10 — k-QUAD-interleaved W3T4/WhhT4 ([k/4][n][4]) GEMVs with
//     coalesced float4 loads (4x fewer load instrs, bitwise-identical order).
//     Measured ~6-9 us vs 16.5 before.

#define B_ 128
#define CAP 40
#define XW 1536   // X row: [buf_h 0:512 | s1_h 512:1024 | s2_h 1024:1536]
#define GSPLIT 12
#define LSPLIT 8
#define NSTEP 64

__device__ __forceinline__ float sigm(float x) { return 1.f / (1.f + expf(-x)); }

// ---------------- repack weights ----------------
// W1T[k][n], k in [0,1536): W_ih[n][k].                               N=1024
// W2T[k][n], k in [0,1024): k<512 -> W_right[n][k], else W_left[n][k-512]. N=2560
// W3T4[k4][col][i] = W_track[col][4*k4+i]   (64 x 2560 x 4)
// WhhT4[k4][n][i]  = W_hh[n][4*k4+i]        (64 x 1024 x 4)
__global__ void k_repack(const float* __restrict__ W_ih, const float* __restrict__ W_hh,
                         const float* __restrict__ W_left, const float* __restrict__ W_right,
                         const float* __restrict__ W_track, const float* __restrict__ b_ih,
                         const float* __restrict__ b_hh,
                         float* __restrict__ W1T, float* __restrict__ W2T,
                         float* __restrict__ W3T4, float* __restrict__ WhhT4,
                         float* __restrict__ b1) {
    size_t idx = (size_t)blockIdx.x * 256 + threadIdx.x;
    const size_t n1 = 1536ull * 1024ull;        // 1,572,864
    const size_t n2 = 1024ull * 2560ull;        // 2,621,440
    const size_t n3 = 64ull * 2560ull * 4ull;   //   655,360
    const size_t n4 = 64ull * 1024ull * 4ull;   //   262,144
    if (idx < n1) {
        int k = (int)(idx >> 10), n = (int)(idx & 1023);
        W1T[idx] = W_ih[(size_t)n * 1536 + k];
    } else if (idx < n1 + n2) {
        size_t r = idx - n1;
        int k = (int)(r / 2560), n = (int)(r % 2560);
        W2T[r] = (k < 512) ? W_right[(size_t)n * 512 + k] : W_left[(size_t)n * 512 + (k - 512)];
    } else if (idx < n1 + n2 + n3) {
        size_t r = idx - n1 - n2;
        int k4 = (int)(r / 10240);
        int rem = (int)(r % 10240);
        int col = rem >> 2, i = rem & 3;
        W3T4[r] = W_track[(size_t)col * 256 + k4 * 4 + i];
    } else if (idx < n1 + n2 + n3 + n4) {
        size_t r = idx - n1 - n2 - n3;
        int k4 = (int)(r >> 12);
        int rem = (int)(r & 4095);
        int n = rem >> 2, i = rem & 3;
        WhhT4[r] = W_hh[(size_t)n * 256 + k4 * 4 + i];
    } else if (idx < n1 + n2 + n3 + n4 + 1024) {
        int i = (int)(idx - n1 - n2 - n3 - n4);
        b1[i] = b_ih[i] + b_hh[i];
    }
}

// ---------------- init state ----------------
__global__ void k_init(const float* __restrict__ buffers, float* __restrict__ stack,
                       float* __restrict__ X, float* __restrict__ tc,
                       float* __restrict__ hh,
                       int* __restrict__ sptr, int* __restrict__ blen) {
    int b = blockIdx.x, t = threadIdx.x;
    const float* b0 = buffers + (size_t)b * 40 * 1024;      // buffers[b][0]
    const float* btop = b0 + 39 * 1024;                     // buffers[b][39]
    float* stk = stack + (size_t)b * CAP * 1024;
    for (int j = t; j < 1024; j += 256) { stk[j] = b0[j]; stk[1024 + j] = b0[j]; }
    float* Xb = X + (size_t)b * XW;
    for (int j = t; j < 512; j += 256) {
        Xb[j] = btop[j]; Xb[512 + j] = b0[j]; Xb[1024 + j] = b0[j];
    }
    tc[b * 256 + t] = 0.f;
    for (int j = t; j < 1024; j += 256) hh[(size_t)b * 1024 + j] = 0.f;  // th0 = 0
    if (t == 0) { sptr[b] = 2; blen[b] = 40; }
}

// ---------------- A: fused tiled fp32 GEMM (gates-x || lstm5-sub), k-split partials --
// [0,192):  gates-x: ks=bid>>4 (12), n0=(bid&15)*64, K-chunk=[ks*128,+128), aoff=0
// [192,512): lstm5:  ks=tI/40  (8),  n0=(tI%40)*64,  K-chunk=[ks*128,+128), aoff=512
// per block: 128x64 output tile, 256 threads, acc 8x4, KT=32 inner staging.
__global__ __launch_bounds__(256, 3) void k_gemm(const float* __restrict__ X,
                                                 const float* __restrict__ W1T,
                                                 const float* __restrict__ W2T,
                                                 float* __restrict__ gpart,
                                                 float* __restrict__ lpart) {
    __shared__ float As[32][132];
    __shared__ float Ws[32][68];
    const int bid = blockIdx.x;
    const float* WT; float* out; int N, n0, k0, aoff;
    if (bid < 192) {
        int ks = bid >> 4, nb = bid & 15;
        WT = W1T; out = gpart + (size_t)ks * 131072;
        N = 1024; n0 = nb * 64; k0 = ks * 128; aoff = 0;
    } else {
        int tI = bid - 192; int ks = tI / 40, nb = tI % 40;
        WT = W2T; out = lpart + (size_t)ks * 327680;
        N = 2560; n0 = nb * 64; k0 = ks * 128; aoff = 512;
    }
    const int tid = threadIdx.x;
    const int tm = tid >> 4;      // 0..15
    const int tn = tid & 15;      // 0..15

    float acc[8][4];
#pragma unroll
    for (int i = 0; i < 8; i++)
#pragma unroll
        for (int j = 0; j < 4; j++) acc[i][j] = 0.f;

    for (int ki = 0; ki < 128; ki += 32) {
        const int kb = k0 + ki;
        __syncthreads();
        {   // stage A: As[kk][m] = X[m][aoff+kb+kk] ; 2 threads per row, 16 floats each
            int m = tid >> 1;
            int c8 = (tid & 1) * 16;
            const float4* src = (const float4*)(X + (size_t)m * XW + aoff + kb + c8);
#pragma unroll
            for (int j = 0; j < 4; j++) {
                float4 v = src[j];
                int kk = c8 + j * 4;
                As[kk + 0][m] = v.x; As[kk + 1][m] = v.y; As[kk + 2][m] = v.z; As[kk + 3][m] = v.w;
            }
        }
        {   // stage W: Ws[kk][c..c+7] = WT[kb+kk][n0+c..] ; 8 threads per k-row
            int kk = tid >> 3;
            int c = (tid & 7) * 8;
            const float4* src = (const float4*)(WT + (size_t)(kb + kk) * N + n0 + c);
            float4* dst = (float4*)(&Ws[kk][c]);
            dst[0] = src[0]; dst[1] = src[1];
        }
        __syncthreads();
#pragma unroll 4
        for (int kk = 0; kk < 32; kk++) {
            float a[8], w[4];
            *(float4*)&a[0] = *(const float4*)&As[kk][tm * 4];
            *(float4*)&a[4] = *(const float4*)&As[kk][64 + tm * 4];
            *(float4*)&w[0] = *(const float4*)&Ws[kk][tn * 4];
#pragma unroll
            for (int i = 0; i < 8; i++)
#pragma unroll
                for (int j = 0; j < 4; j++) acc[i][j] += a[i] * w[j];
        }
    }
    float* base = out + n0 + tn * 4;
#pragma unroll
    for (int i = 0; i < 8; i++) {
        int m = (i < 4) ? (tm * 4 + i) : (64 + tm * 4 + (i - 4));
        *(float4*)(base + (size_t)m * N) = make_float4(acc[i][0], acc[i][1], acc[i][2], acc[i][3]);
    }
}

// ---------------- B: LSTM + argmax + hh-GEMM + track-GEMM + node + stack + next-X ----
// grid 512 = 128 rows x 4 j-slices (q). All 4 q-blocks of a row redundantly compute the
// LSTM/logits/argmax (deterministic, identical); slice work is split by q.
__global__ __launch_bounds__(256) void k_B(const float* __restrict__ gpart,
                                           const float* __restrict__ lpart,
                                           const float* __restrict__ hh_in,
                                           float* __restrict__ hh_out,
                                           const float* __restrict__ b1,
                                           const float* __restrict__ b_left,
                                           const float* __restrict__ W3T4,
                                           const float* __restrict__ WhhT4,
                                           const float* __restrict__ W_trans,
                                           const float* __restrict__ b_trans,
                                           const float* __restrict__ buffers,
                                           float* __restrict__ stack,
                                           float* __restrict__ X,
                                           const float* __restrict__ tc_in,
                                           float* __restrict__ tc_out,
                                           const int* __restrict__ sp_in,
                                           int* __restrict__ sp_out,
                                           const int* __restrict__ bl_in,
                                           int* __restrict__ bl_out,
                                           float* __restrict__ out_s) {
    const int bid = blockIdx.x;
    const int b = bid >> 2, q = bid & 3;
    const int t = threadIdx.x;
    const int sp = sp_in[b], bl = bl_in[b];
    __shared__ float sh_th[256];
    __shared__ float redw[4][4];
    __shared__ float shg[5][128];

    // 1) gather gates partials (12 splits + hh lump) + LSTM cell
    const float* gp = gpart + (size_t)b * 1024;
    const float* hp = hh_in + (size_t)b * 1024;
    float gi = b1[t] + hp[t],             gf = b1[256 + t] + hp[256 + t];
    float gg = b1[512 + t] + hp[512 + t], go = b1[768 + t] + hp[768 + t];
#pragma unroll 4
    for (int kc = 0; kc < GSPLIT; kc++) {
        const float* p = gp + (size_t)kc * 131072;
        gi += p[t]; gf += p[256 + t]; gg += p[512 + t]; go += p[768 + t];
    }
    float tcv = tc_in[b * 256 + t];
    float tcn = sigm(gf) * tcv + sigm(gi) * tanhf(gg);
    float thn = sigm(go) * tanhf(tcn);
    if ((t >> 6) == q) tc_out[b * 256 + t] = tcn;
    sh_th[t] = thn;

    // 2) logits via wave shfl reduction + argmax (all threads identically)
    float v0 = thn * W_trans[t],       v1 = thn * W_trans[256 + t];
    float v2 = thn * W_trans[512 + t], v3 = thn * W_trans[768 + t];
#pragma unroll
    for (int off = 32; off > 0; off >>= 1) {
        v0 += __shfl_down(v0, off); v1 += __shfl_down(v1, off);
        v2 += __shfl_down(v2, off); v3 += __shfl_down(v3, off);
    }
    if ((t & 63) == 0) {
        int w = t >> 6;
        redw[w][0] = v0; redw[w][1] = v1; redw[w][2] = v2; redw[w][3] = v3;
    }
    __syncthreads();                       // redw + sh_th ready
    float lg0 = redw[0][0] + redw[1][0] + redw[2][0] + redw[3][0] + b_trans[0];
    float lg1 = redw[0][1] + redw[1][1] + redw[2][1] + redw[3][1] + b_trans[1];
    float lg2 = redw[0][2] + redw[1][2] + redw[2][2] + redw[3][2] + b_trans[2];
    float lg3 = redw[0][3] + redw[1][3] + redw[2][3] + redw[3][3] + b_trans[3];
    int tr = 0; float best = lg0;
    if (lg1 > best) { best = lg1; tr = 1; }
    if (lg2 > best) { best = lg2; tr = 2; }
    if (lg3 > best) { best = lg3; tr = 3; }
    const bool do_shift = (tr == 3) && (bl > 2);
    const bool do_red   = (tr == 2) && (sp > 3);
    const int spn = sp + (do_shift ? 1 : 0) - (do_red ? 1 : 0);
    const int bln = bl - (do_shift ? 1 : 0);
    if (q == 0 && t == 0) {
        out_s[b * 4 + 0] = lg0; out_s[b * 4 + 1] = lg1;
        out_s[b * 4 + 2] = lg2; out_s[b * 4 + 3] = lg3;
        sp_out[b] = spn; bl_out[b] = bln;
    }
    float* stk = stack + (size_t)b * CAP * 1024;

    // 3) hh-GEMM for NEXT step's gates: k-quad-interleaved WhhT4, float4 coalesced.
    //    Summation grouping (k mod 4 -> h0..h3) identical to champion.
    {
        const float* wh = WhhT4 + (size_t)(q * 256 + t) * 4;
        float h0 = 0, h1 = 0, h2 = 0, h3 = 0;
#pragma unroll 8
        for (int k4 = 0; k4 < 64; k4++) {
            float4 w = *(const float4*)(wh + (size_t)k4 * 4096);
            h0 += sh_th[4 * k4]     * w.x;
            h1 += sh_th[4 * k4 + 1] * w.y;
            h2 += sh_th[4 * k4 + 2] * w.z;
            h3 += sh_th[4 * k4 + 3] * w.w;
        }
        hh_out[(size_t)b * 1024 + q * 256 + t] = (h0 + h1) + (h2 + h3);
    }

    // 4) reduce rows: lstm5 = sub-partials + b_left + W_track@th_new ; node.
    //    kh = t>>7: half-waves split the K range (128 each) and LSPLIT halves.
    //    W3T4 k-quad-interleaved: float4 loads, sequential-k order per accumulator.
    const int jj = t & 127, kh = t >> 7, j = q * 128 + jj;
    float node_h = 0.f;
    float a, ii, f1, f2, oo;
    if (do_red) {
        if (kh == 0) {
            a  = b_left[j];        ii = b_left[512 + j]; f1 = b_left[1024 + j];
            f2 = b_left[1536 + j]; oo = b_left[2048 + j];
        } else { a = ii = f1 = f2 = oo = 0.f; }
        const float* lp = lpart + (size_t)b * 2560;
        const int half = LSPLIT >> 1;
        for (int kc = kh * half; kc < kh * half + half; kc++) {
            const float* p = lp + (size_t)kc * 327680;
            a += p[j]; ii += p[512 + j]; f1 += p[1024 + j]; f2 += p[1536 + j]; oo += p[2048 + j];
        }
        const float* w = W3T4 + (size_t)j * 4;
#pragma unroll 4
        for (int k4 = kh * 32; k4 < kh * 32 + 32; k4++) {
            float t0 = sh_th[4 * k4],     t1 = sh_th[4 * k4 + 1];
            float t2 = sh_th[4 * k4 + 2], t3 = sh_th[4 * k4 + 3];
            const float* wk = w + (size_t)k4 * 10240;
            float4 wv;
            wv = *(const float4*)(wk);        a  += t0 * wv.x; a  += t1 * wv.y; a  += t2 * wv.z; a  += t3 * wv.w;
            wv = *(const float4*)(wk + 2048); ii += t0 * wv.x; ii += t1 * wv.y; ii += t2 * wv.z; ii += t3 * wv.w;
            wv = *(const float4*)(wk + 4096); f1 += t0 * wv.x; f1 += t1 * wv.y; f1 += t2 * wv.z; f1 += t3 * wv.w;
            wv = *(const float4*)(wk + 6144); f2 += t0 * wv.x; f2 += t1 * wv.y; f2 += t2 * wv.z; f2 += t3 * wv.w;
            wv = *(const float4*)(wk + 8192); oo += t0 * wv.x; oo += t1 * wv.y; oo += t2 * wv.z; oo += t3 * wv.w;
        }
        if (kh == 1) {
            shg[0][jj] = a; shg[1][jj] = ii; shg[2][jj] = f1; shg[3][jj] = f2; shg[4][jj] = oo;
        }
    }
    __syncthreads();                       // do_red is block-uniform
    if (do_red && kh == 0) {
        a += shg[0][jj]; ii += shg[1][jj]; f1 += shg[2][jj];
        f2 += shg[3][jj]; oo += shg[4][jj];
        float s1c = stk[(size_t)(sp - 1) * 1024 + 512 + j];
        float s2c = stk[(size_t)(sp - 2) * 1024 + 512 + j];
        float c = tanhf(a) * sigm(ii) + sigm(f1) * s2c + sigm(f2) * s1c;
        float h = sigm(oo) * tanhf(c);
        stk[(size_t)(sp - 2) * 1024 + j] = h;          // own-slice addresses only
        stk[(size_t)(sp - 2) * 1024 + 512 + j] = c;
        node_h = h;
    }
    // 5) shift: push buf_top (slot sp untouched by any read this step)
    if (do_shift) {
        const float* bt = buffers + ((size_t)b * 40 + (bl - 1)) * 1024;
        const int idx = q * 256 + t;
        stk[(size_t)sp * 1024 + idx] = bt[idx];
    }
    // 6) build next X (slice j, kh==0 threads)
    float* Xb = X + (size_t)b * XW;
    if (kh == 0) {
        const float* btn = buffers + ((size_t)b * 40 + (bln - 1)) * 1024;
        Xb[j] = btn[j];                                 // buf_top' h
        float s1h;
        if (do_red)        s1h = node_h;                // just-built node (register)
        else if (do_shift) s1h = buffers[((size_t)b * 40 + (bl - 1)) * 1024 + j];
        else               s1h = stk[(size_t)(sp - 1) * 1024 + j];
        Xb[512 + j] = s1h;
        Xb[1024 + j] = stk[(size_t)(spn - 2) * 1024 + j];  // untouched slot in all 3 cases
    }
}

// ---------------- host ----------------
extern "C" void kernel_launch(void* const* d_in, const int* in_sizes, int n_in,
                              void* d_out, int out_size, void* d_ws, size_t ws_size,
                              hipStream_t stream) {
    const float* buffers = (const float*)d_in[0];
    const float* W_left  = (const float*)d_in[1];
    const float* b_left  = (const float*)d_in[2];
    const float* W_right = (const float*)d_in[3];
    const float* W_track = (const float*)d_in[4];
    const float* W_ih    = (const float*)d_in[5];
    const float* W_hh    = (const float*)d_in[6];
    const float* b_ih    = (const float*)d_in[7];
    const float* b_hh    = (const float*)d_in[8];
    const float* W_trans = (const float*)d_in[9];
    const float* b_trans = (const float*)d_in[10];
    float* out = (float*)d_out;

    float* ws = (float*)d_ws;
    size_t off = 0;
    float* W1T   = ws + off; off += 1536ull * 1024;             // 1,572,864
    float* W2T   = ws + off; off += 1024ull * 2560;             // 2,621,440
    float* W3T4  = ws + off; off += 64ull * 2560 * 4;           //   655,360
    float* WhhT4 = ws + off; off += 64ull * 1024 * 4;           //   262,144
    float* b1    = ws + off; off += 1024;
    float* X     = ws + off; off += (size_t)B_ * XW;            //   196,608
    float* tc_a  = ws + off; off += (size_t)B_ * 256;
    float* tc_b  = ws + off; off += (size_t)B_ * 256;
    float* hh_a  = ws + off; off += (size_t)B_ * 1024;          //   131,072
    float* hh_b  = ws + off; off += (size_t)B_ * 1024;
    float* gpart = ws + off; off += (size_t)GSPLIT * 131072;    // 1,572,864
    float* lpart = ws + off; off += (size_t)LSPLIT * 327680;    // 2,621,440
    float* stack = ws + off; off += (size_t)B_ * CAP * 1024;    // 5,242,880
    int* sp_a = (int*)(ws + off); off += 128;
    int* sp_b = (int*)(ws + off); off += 128;
    int* bl_a = (int*)(ws + off); off += 128;
    int* bl_b = (int*)(ws + off); off += 128;

    {
        size_t total = 1536ull * 1024 + 1024ull * 2560 + 64ull * 2560 * 4
                     + 64ull * 1024 * 4 + 1024;
        int blocks = (int)((total + 255) / 256);
        k_repack<<<blocks, 256, 0, stream>>>(W_ih, W_hh, W_left, W_right, W_track, b_ih, b_hh,
                                             W1T, W2T, W3T4, WhhT4, b1);
        k_init<<<B_, 256, 0, stream>>>(buffers, stack, X, tc_a, hh_a, sp_a, bl_a);
    }

    for (int s = 0; s < NSTEP; s++) {
        k_gemm<<<512, 256, 0, stream>>>(X, W1T, W2T, gpart, lpart);
        const float* tci = (s & 1) ? tc_b : tc_a;  float* tco = (s & 1) ? tc_a : tc_b;
        const float* hhi = (s & 1) ? hh_b : hh_a;  float* hho = (s & 1) ? hh_a : hh_b;
        const int*   spi = (s & 1) ? sp_b : sp_a;  int*   spo = (s & 1) ? sp_a : sp_b;
        const int*   bli = (s & 1) ? bl_b : bl_a;  int*   blo = (s & 1) ? bl_a : bl_b;
        k_B<<<512, 256, 0, stream>>>(gpart, lpart, hhi, hho, b1, b_left, W3T4, WhhT4,
                                     W_trans, b_trans, buffers, stack, X, tci, tco,
                                     spi, spo, bli, blo, out + (size_t)s * B_ * 4);
    }
    (void)in_sizes; (void)n_in; (void)out_size; (void)ws_size;
}

// Round 12
// 2234.006 us; speedup vs baseline: 1.8033x; 1.0138x over previous
//
#include <hip/hip_runtime.h>
#include <math.h>

// SPINN forward, fp32 throughout (argmax trajectory sensitivity forbids bf16/f16).
// 2 launches/step:
//   A (k_gemm, 1024 blk x 128 thr): fused GEMM [gates-x 12x32 || lstm5 8x80],
//     tile 128x32, acc 8x4, KS=128 (same splits/partial layout as champion).
//     4 blocks/CU x 2 waves = 8 waves/CU with 4 independent barrier domains ->
//     staging of one block overlaps compute of three others (vs 2 at 512x256).
//     LDS read ratio unchanged (3 ds_read_b128 / 32 FMA, proven floor).
//   B (k_B, 512 blk = row x 4 j-slices): unchanged round-11 — gather + LSTM +
//     argmax + k-QUAD-interleaved WhhT4/W3T4 GEMVs (coalesced float4) + node +
//     stack + next-X.

#define B_ 128
#define CAP 40
#define XW 1536   // X row: [buf_h 0:512 | s1_h 512:1024 | s2_h 1024:1536]
#define GSPLIT 12
#define LSPLIT 8
#define NSTEP 64

__device__ __forceinline__ float sigm(float x) { return 1.f / (1.f + expf(-x)); }

// ---------------- repack weights ----------------
// W1T[k][n], k in [0,1536): W_ih[n][k].                               N=1024
// W2T[k][n], k in [0,1024): k<512 -> W_right[n][k], else W_left[n][k-512]. N=2560
// W3T4[k4][col][i] = W_track[col][4*k4+i]   (64 x 2560 x 4)
// WhhT4[k4][n][i]  = W_hh[n][4*k4+i]        (64 x 1024 x 4)
__global__ void k_repack(const float* __restrict__ W_ih, const float* __restrict__ W_hh,
                         const float* __restrict__ W_left, const float* __restrict__ W_right,
                         const float* __restrict__ W_track, const float* __restrict__ b_ih,
                         const float* __restrict__ b_hh,
                         float* __restrict__ W1T, float* __restrict__ W2T,
                         float* __restrict__ W3T4, float* __restrict__ WhhT4,
                         float* __restrict__ b1) {
    size_t idx = (size_t)blockIdx.x * 256 + threadIdx.x;
    const size_t n1 = 1536ull * 1024ull;        // 1,572,864
    const size_t n2 = 1024ull * 2560ull;        // 2,621,440
    const size_t n3 = 64ull * 2560ull * 4ull;   //   655,360
    const size_t n4 = 64ull * 1024ull * 4ull;   //   262,144
    if (idx < n1) {
        int k = (int)(idx >> 10), n = (int)(idx & 1023);
        W1T[idx] = W_ih[(size_t)n * 1536 + k];
    } else if (idx < n1 + n2) {
        size_t r = idx - n1;
        int k = (int)(r / 2560), n = (int)(r % 2560);
        W2T[r] = (k < 512) ? W_right[(size_t)n * 512 + k] : W_left[(size_t)n * 512 + (k - 512)];
    } else if (idx < n1 + n2 + n3) {
        size_t r = idx - n1 - n2;
        int k4 = (int)(r / 10240);
        int rem = (int)(r % 10240);
        int col = rem >> 2, i = rem & 3;
        W3T4[r] = W_track[(size_t)col * 256 + k4 * 4 + i];
    } else if (idx < n1 + n2 + n3 + n4) {
        size_t r = idx - n1 - n2 - n3;
        int k4 = (int)(r >> 12);
        int rem = (int)(r & 4095);
        int n = rem >> 2, i = rem & 3;
        WhhT4[r] = W_hh[(size_t)n * 256 + k4 * 4 + i];
    } else if (idx < n1 + n2 + n3 + n4 + 1024) {
        int i = (int)(idx - n1 - n2 - n3 - n4);
        b1[i] = b_ih[i] + b_hh[i];
    }
}

// ---------------- init state ----------------
__global__ void k_init(const float* __restrict__ buffers, float* __restrict__ stack,
                       float* __restrict__ X, float* __restrict__ tc,
                       float* __restrict__ hh,
                       int* __restrict__ sptr, int* __restrict__ blen) {
    int b = blockIdx.x, t = threadIdx.x;
    const float* b0 = buffers + (size_t)b * 40 * 1024;      // buffers[b][0]
    const float* btop = b0 + 39 * 1024;                     // buffers[b][39]
    float* stk = stack + (size_t)b * CAP * 1024;
    for (int j = t; j < 1024; j += 256) { stk[j] = b0[j]; stk[1024 + j] = b0[j]; }
    float* Xb = X + (size_t)b * XW;
    for (int j = t; j < 512; j += 256) {
        Xb[j] = btop[j]; Xb[512 + j] = b0[j]; Xb[1024 + j] = b0[j];
    }
    tc[b * 256 + t] = 0.f;
    for (int j = t; j < 1024; j += 256) hh[(size_t)b * 1024 + j] = 0.f;  // th0 = 0
    if (t == 0) { sptr[b] = 2; blen[b] = 40; }
}

// ---------------- A: fused tiled fp32 GEMM (gates-x || lstm5-sub), k-split partials --
// [0,384):   gates-x: ks=bid/32 (12), n0=(bid%32)*32, K-chunk=[ks*128,+128), aoff=0
// [384,1024): lstm5:  ks=tI/80  (8),  n0=(tI%80)*32,  K-chunk=[ks*128,+128), aoff=512
// 128 threads: tile 128x32, thread-grid 16(m)x8(n), acc 8x4, KT=32 inner staging.
__global__ __launch_bounds__(128, 2) void k_gemm(const float* __restrict__ X,
                                                 const float* __restrict__ W1T,
                                                 const float* __restrict__ W2T,
                                                 float* __restrict__ gpart,
                                                 float* __restrict__ lpart) {
    __shared__ float As[32][132];   // 16.9 KB
    __shared__ float Ws[32][36];    //  4.6 KB
    const int bid = blockIdx.x;
    const float* WT; float* out; int N, n0, k0, aoff;
    if (bid < 384) {
        int ks = bid >> 5, nb = bid & 31;
        WT = W1T; out = gpart + (size_t)ks * 131072;
        N = 1024; n0 = nb * 32; k0 = ks * 128; aoff = 0;
    } else {
        int tI = bid - 384; int ks = tI / 80, nb = tI % 80;
        WT = W2T; out = lpart + (size_t)ks * 327680;
        N = 2560; n0 = nb * 32; k0 = ks * 128; aoff = 512;
    }
    const int tid = threadIdx.x;
    const int tm = tid >> 3;      // 0..15
    const int tn = tid & 7;       // 0..7

    float acc[8][4];
#pragma unroll
    for (int i = 0; i < 8; i++)
#pragma unroll
        for (int j = 0; j < 4; j++) acc[i][j] = 0.f;

    for (int ki = 0; ki < 128; ki += 32) {
        const int kb = k0 + ki;
        __syncthreads();
        {   // stage A: rows m and m+64, 16 floats each (2 threads/row, 2 passes)
            int m = tid >> 1;
            int c8 = (tid & 1) * 16;
            const float4* s0 = (const float4*)(X + (size_t)m * XW + aoff + kb + c8);
            const float4* s1 = (const float4*)(X + (size_t)(m + 64) * XW + aoff + kb + c8);
#pragma unroll
            for (int j = 0; j < 4; j++) {
                float4 v = s0[j];
                int kk = c8 + j * 4;
                As[kk + 0][m] = v.x; As[kk + 1][m] = v.y; As[kk + 2][m] = v.z; As[kk + 3][m] = v.w;
            }
#pragma unroll
            for (int j = 0; j < 4; j++) {
                float4 v = s1[j];
                int kk = c8 + j * 4;
                As[kk + 0][m + 64] = v.x; As[kk + 1][m + 64] = v.y;
                As[kk + 2][m + 64] = v.z; As[kk + 3][m + 64] = v.w;
            }
        }
        {   // stage W: Ws[kk][c..c+7] = WT[kb+kk][n0+c..] ; 4 threads per k-row
            int kk = tid >> 2;
            int c = (tid & 3) * 8;
            const float4* src = (const float4*)(WT + (size_t)(kb + kk) * N + n0 + c);
            float4* dst = (float4*)(&Ws[kk][c]);
            dst[0] = src[0]; dst[1] = src[1];
        }
        __syncthreads();
#pragma unroll 4
        for (int kk = 0; kk < 32; kk++) {
            float a[8], w[4];
            *(float4*)&a[0] = *(const float4*)&As[kk][tm * 4];
            *(float4*)&a[4] = *(const float4*)&As[kk][64 + tm * 4];
            *(float4*)&w[0] = *(const float4*)&Ws[kk][tn * 4];
#pragma unroll
            for (int i = 0; i < 8; i++)
#pragma unroll
                for (int j = 0; j < 4; j++) acc[i][j] += a[i] * w[j];
        }
    }
    float* base = out + n0 + tn * 4;
#pragma unroll
    for (int i = 0; i < 8; i++) {
        int m = (i < 4) ? (tm * 4 + i) : (64 + tm * 4 + (i - 4));
        *(float4*)(base + (size_t)m * N) = make_float4(acc[i][0], acc[i][1], acc[i][2], acc[i][3]);
    }
}

// ---------------- B: LSTM + argmax + hh-GEMM + track-GEMM + node + stack + next-X ----
// grid 512 = 128 rows x 4 j-slices (q). All 4 q-blocks of a row redundantly compute the
// LSTM/logits/argmax (deterministic, identical); slice work is split by q.
__global__ __launch_bounds__(256) void k_B(const float* __restrict__ gpart,
                                           const float* __restrict__ lpart,
                                           const float* __restrict__ hh_in,
                                           float* __restrict__ hh_out,
                                           const float* __restrict__ b1,
                                           const float* __restrict__ b_left,
                                           const float* __restrict__ W3T4,
                                           const float* __restrict__ WhhT4,
                                           const float* __restrict__ W_trans,
                                           const float* __restrict__ b_trans,
                                           const float* __restrict__ buffers,
                                           float* __restrict__ stack,
                                           float* __restrict__ X,
                                           const float* __restrict__ tc_in,
                                           float* __restrict__ tc_out,
                                           const int* __restrict__ sp_in,
                                           int* __restrict__ sp_out,
                                           const int* __restrict__ bl_in,
                                           int* __restrict__ bl_out,
                                           float* __restrict__ out_s) {
    const int bid = blockIdx.x;
    const int b = bid >> 2, q = bid & 3;
    const int t = threadIdx.x;
    const int sp = sp_in[b], bl = bl_in[b];
    __shared__ float sh_th[256];
    __shared__ float redw[4][4];
    __shared__ float shg[5][128];

    // 1) gather gates partials (12 splits + hh lump) + LSTM cell
    const float* gp = gpart + (size_t)b * 1024;
    const float* hp = hh_in + (size_t)b * 1024;
    float gi = b1[t] + hp[t],             gf = b1[256 + t] + hp[256 + t];
    float gg = b1[512 + t] + hp[512 + t], go = b1[768 + t] + hp[768 + t];
#pragma unroll 4
    for (int kc = 0; kc < GSPLIT; kc++) {
        const float* p = gp + (size_t)kc * 131072;
        gi += p[t]; gf += p[256 + t]; gg += p[512 + t]; go += p[768 + t];
    }
    float tcv = tc_in[b * 256 + t];
    float tcn = sigm(gf) * tcv + sigm(gi) * tanhf(gg);
    float thn = sigm(go) * tanhf(tcn);
    if ((t >> 6) == q) tc_out[b * 256 + t] = tcn;
    sh_th[t] = thn;

    // 2) logits via wave shfl reduction + argmax (all threads identically)
    float v0 = thn * W_trans[t],       v1 = thn * W_trans[256 + t];
    float v2 = thn * W_trans[512 + t], v3 = thn * W_trans[768 + t];
#pragma unroll
    for (int off = 32; off > 0; off >>= 1) {
        v0 += __shfl_down(v0, off); v1 += __shfl_down(v1, off);
        v2 += __shfl_down(v2, off); v3 += __shfl_down(v3, off);
    }
    if ((t & 63) == 0) {
        int w = t >> 6;
        redw[w][0] = v0; redw[w][1] = v1; redw[w][2] = v2; redw[w][3] = v3;
    }
    __syncthreads();                       // redw + sh_th ready
    float lg0 = redw[0][0] + redw[1][0] + redw[2][0] + redw[3][0] + b_trans[0];
    float lg1 = redw[0][1] + redw[1][1] + redw[2][1] + redw[3][1] + b_trans[1];
    float lg2 = redw[0][2] + redw[1][2] + redw[2][2] + redw[3][2] + b_trans[2];
    float lg3 = redw[0][3] + redw[1][3] + redw[2][3] + redw[3][3] + b_trans[3];
    int tr = 0; float best = lg0;
    if (lg1 > best) { best = lg1; tr = 1; }
    if (lg2 > best) { best = lg2; tr = 2; }
    if (lg3 > best) { best = lg3; tr = 3; }
    const bool do_shift = (tr == 3) && (bl > 2);
    const bool do_red   = (tr == 2) && (sp > 3);
    const int spn = sp + (do_shift ? 1 : 0) - (do_red ? 1 : 0);
    const int bln = bl - (do_shift ? 1 : 0);
    if (q == 0 && t == 0) {
        out_s[b * 4 + 0] = lg0; out_s[b * 4 + 1] = lg1;
        out_s[b * 4 + 2] = lg2; out_s[b * 4 + 3] = lg3;
        sp_out[b] = spn; bl_out[b] = bln;
    }
    float* stk = stack + (size_t)b * CAP * 1024;

    // 3) hh-GEMM for NEXT step's gates: k-quad-interleaved WhhT4, float4 coalesced.
    //    Summation grouping (k mod 4 -> h0..h3) identical to champion.
    {
        const float* wh = WhhT4 + (size_t)(q * 256 + t) * 4;
        float h0 = 0, h1 = 0, h2 = 0, h3 = 0;
#pragma unroll 8
        for (int k4 = 0; k4 < 64; k4++) {
            float4 w = *(const float4*)(wh + (size_t)k4 * 4096);
            h0 += sh_th[4 * k4]     * w.x;
            h1 += sh_th[4 * k4 + 1] * w.y;
            h2 += sh_th[4 * k4 + 2] * w.z;
            h3 += sh_th[4 * k4 + 3] * w.w;
        }
        hh_out[(size_t)b * 1024 + q * 256 + t] = (h0 + h1) + (h2 + h3);
    }

    // 4) reduce rows: lstm5 = sub-partials + b_left + W_track@th_new ; node.
    //    kh = t>>7: half-waves split the K range (128 each) and LSPLIT halves.
    //    W3T4 k-quad-interleaved: float4 loads, sequential-k order per accumulator.
    const int jj = t & 127, kh = t >> 7, j = q * 128 + jj;
    float node_h = 0.f;
    float a, ii, f1, f2, oo;
    if (do_red) {
        if (kh == 0) {
            a  = b_left[j];        ii = b_left[512 + j]; f1 = b_left[1024 + j];
            f2 = b_left[1536 + j]; oo = b_left[2048 + j];
        } else { a = ii = f1 = f2 = oo = 0.f; }
        const float* lp = lpart + (size_t)b * 2560;
        const int half = LSPLIT >> 1;
        for (int kc = kh * half; kc < kh * half + half; kc++) {
            const float* p = lp + (size_t)kc * 327680;
            a += p[j]; ii += p[512 + j]; f1 += p[1024 + j]; f2 += p[1536 + j]; oo += p[2048 + j];
        }
        const float* w = W3T4 + (size_t)j * 4;
#pragma unroll 4
        for (int k4 = kh * 32; k4 < kh * 32 + 32; k4++) {
            float t0 = sh_th[4 * k4],     t1 = sh_th[4 * k4 + 1];
            float t2 = sh_th[4 * k4 + 2], t3 = sh_th[4 * k4 + 3];
            const float* wk = w + (size_t)k4 * 10240;
            float4 wv;
            wv = *(const float4*)(wk);        a  += t0 * wv.x; a  += t1 * wv.y; a  += t2 * wv.z; a  += t3 * wv.w;
            wv = *(const float4*)(wk + 2048); ii += t0 * wv.x; ii += t1 * wv.y; ii += t2 * wv.z; ii += t3 * wv.w;
            wv = *(const float4*)(wk + 4096); f1 += t0 * wv.x; f1 += t1 * wv.y; f1 += t2 * wv.z; f1 += t3 * wv.w;
            wv = *(const float4*)(wk + 6144); f2 += t0 * wv.x; f2 += t1 * wv.y; f2 += t2 * wv.z; f2 += t3 * wv.w;
            wv = *(const float4*)(wk + 8192); oo += t0 * wv.x; oo += t1 * wv.y; oo += t2 * wv.z; oo += t3 * wv.w;
        }
        if (kh == 1) {
            shg[0][jj] = a; shg[1][jj] = ii; shg[2][jj] = f1; shg[3][jj] = f2; shg[4][jj] = oo;
        }
    }
    __syncthreads();                       // do_red is block-uniform
    if (do_red && kh == 0) {
        a += shg[0][jj]; ii += shg[1][jj]; f1 += shg[2][jj];
        f2 += shg[3][jj]; oo += shg[4][jj];
        float s1c = stk[(size_t)(sp - 1) * 1024 + 512 + j];
        float s2c = stk[(size_t)(sp - 2) * 1024 + 512 + j];
        float c = tanhf(a) * sigm(ii) + sigm(f1) * s2c + sigm(f2) * s1c;
        float h = sigm(oo) * tanhf(c);
        stk[(size_t)(sp - 2) * 1024 + j] = h;          // own-slice addresses only
        stk[(size_t)(sp - 2) * 1024 + 512 + j] = c;
        node_h = h;
    }
    // 5) shift: push buf_top (slot sp untouched by any read this step)
    if (do_shift) {
        const float* bt = buffers + ((size_t)b * 40 + (bl - 1)) * 1024;
        const int idx = q * 256 + t;
        stk[(size_t)sp * 1024 + idx] = bt[idx];
    }
    // 6) build next X (slice j, kh==0 threads)
    float* Xb = X + (size_t)b * XW;
    if (kh == 0) {
        const float* btn = buffers + ((size_t)b * 40 + (bln - 1)) * 1024;
        Xb[j] = btn[j];                                 // buf_top' h
        float s1h;
        if (do_red)        s1h = node_h;                // just-built node (register)
        else if (do_shift) s1h = buffers[((size_t)b * 40 + (bl - 1)) * 1024 + j];
        else               s1h = stk[(size_t)(sp - 1) * 1024 + j];
        Xb[512 + j] = s1h;
        Xb[1024 + j] = stk[(size_t)(spn - 2) * 1024 + j];  // untouched slot in all 3 cases
    }
}

// ---------------- host ----------------
extern "C" void kernel_launch(void* const* d_in, const int* in_sizes, int n_in,
                              void* d_out, int out_size, void* d_ws, size_t ws_size,
                              hipStream_t stream) {
    const float* buffers = (const float*)d_in[0];
    const float* W_left  = (const float*)d_in[1];
    const float* b_left  = (const float*)d_in[2];
    const float* W_right = (const float*)d_in[3];
    const float* W_track = (const float*)d_in[4];
    const float* W_ih    = (const float*)d_in[5];
    const float* W_hh    = (const float*)d_in[6];
    const float* b_ih    = (const float*)d_in[7];
    const float* b_hh    = (const float*)d_in[8];
    const float* W_trans = (const float*)d_in[9];
    const float* b_trans = (const float*)d_in[10];
    float* out = (float*)d_out;

    float* ws = (float*)d_ws;
    size_t off = 0;
    float* W1T   = ws + off; off += 1536ull * 1024;             // 1,572,864
    float* W2T   = ws + off; off += 1024ull * 2560;             // 2,621,440
    float* W3T4  = ws + off; off += 64ull * 2560 * 4;           //   655,360
    float* WhhT4 = ws + off; off += 64ull * 1024 * 4;           //   262,144
    float* b1    = ws + off; off += 1024;
    float* X     = ws + off; off += (size_t)B_ * XW;            //   196,608
    float* tc_a  = ws + off; off += (size_t)B_ * 256;
    float* tc_b  = ws + off; off += (size_t)B_ * 256;
    float* hh_a  = ws + off; off += (size_t)B_ * 1024;          //   131,072
    float* hh_b  = ws + off; off += (size_t)B_ * 1024;
    float* gpart = ws + off; off += (size_t)GSPLIT * 131072;    // 1,572,864
    float* lpart = ws + off; off += (size_t)LSPLIT * 327680;    // 2,621,440
    float* stack = ws + off; off += (size_t)B_ * CAP * 1024;    // 5,242,880
    int* sp_a = (int*)(ws + off); off += 128;
    int* sp_b = (int*)(ws + off); off += 128;
    int* bl_a = (int*)(ws + off); off += 128;
    int* bl_b = (int*)(ws + off); off += 128;

    {
        size_t total = 1536ull * 1024 + 1024ull * 2560 + 64ull * 2560 * 4
                     + 64ull * 1024 * 4 + 1024;
        int blocks = (int)((total + 255) / 256);
        k_repack<<<blocks, 256, 0, stream>>>(W_ih, W_hh, W_left, W_right, W_track, b_ih, b_hh,
                                             W1T, W2T, W3T4, WhhT4, b1);
        k_init<<<B_, 256, 0, stream>>>(buffers, stack, X, tc_a, hh_a, sp_a, bl_a);
    }

    for (int s = 0; s < NSTEP; s++) {
        k_gemm<<<1024, 128, 0, stream>>>(X, W1T, W2T, gpart, lpart);
        const float* tci = (s & 1) ? tc_b : tc_a;  float* tco = (s & 1) ? tc_a : tc_b;
        const float* hhi = (s & 1) ? hh_b : hh_a;  float* hho = (s & 1) ? hh_a : hh_b;
        const int*   spi = (s & 1) ? sp_b : sp_a;  int*   spo = (s & 1) ? sp_a : sp_b;
        const int*   bli = (s & 1) ? bl_b : bl_a;  int*   blo = (s & 1) ? bl_a : bl_b;
        k_B<<<512, 256, 0, stream>>>(gpart, lpart, hhi, hho, b1, b_left, W3T4, WhhT4,
                                     W_trans, b_trans, buffers, stack, X, tci, tco,
                                     spi, spo, bli, blo, out + (size_t)s * B_ * 4);
    }
    (void)in_sizes; (void)n_in; (void)out_size; (void)ws_size;
}